// Round 5
// baseline (45.087 us; speedup 1.0000x reference)
//
#include <hip/hip_runtime.h>
#include <math.h>

#define NN 1024
#define MM 1024
#define DD 256
#define TILE 64
#define NTB 16
#define PITCH 260  // 256 + 4 pad: conflict-free b128 reads (proven R1/R4)

__device__ inline void merge_ms(float& m, float& s, float m2, float s2) {
  float mn = fmaxf(m, m2);
  s = s * __expf(m - mn) + s2 * __expf(m2 - mn);
  m = mn;
}

__device__ inline float wredSum(float v) {
#pragma unroll
  for (int o = 32; o > 0; o >>= 1) v += __shfl_down(v, o, 64);
  return v;
}

// ---------------- K1: distance tile + S store + row/col softmax partials ----
__global__ __launch_bounds__(256) void k_tile(const float* __restrict__ zx,
                                              const float* __restrict__ zy,
                                              float* __restrict__ S,
                                              float* __restrict__ rowPM,
                                              float* __restrict__ rowPS,
                                              float* __restrict__ colPM,
                                              float* __restrict__ colPS,
                                              int* __restrict__ counter) {
  __shared__ float xs[TILE * PITCH];
  __shared__ float ys[TILE * PITCH];
  const int it = blockIdx.y, jt = blockIdx.x;
  const int i0 = it * TILE, j0 = jt * TILE;
  const int t = threadIdx.x;
  const int tx = t & 15, ty = t >> 4;

  // reset the K2 completion ticket each launch (graph-replay safe)
  if (it == 0 && jt == 0 && t == 0) counter[0] = 0;

  // stage 64 rows x 256 floats of both inputs (R1/R4-proven, coalesced float4)
#pragma unroll
  for (int k = 0; k < 16; ++k) {
    int idx4 = t + k * 256;
    int r = idx4 >> 6;
    int c4 = idx4 & 63;
    float4 vx = reinterpret_cast<const float4*>(zx + (size_t)(i0 + r) * DD)[c4];
    float4 vy = reinterpret_cast<const float4*>(zy + (size_t)(j0 + r) * DD)[c4];
    *reinterpret_cast<float4*>(&xs[r * PITCH + c4 * 4]) = vx;
    *reinterpret_cast<float4*>(&ys[r * PITCH + c4 * 4]) = vy;
  }
  __syncthreads();

  float acc4[4][4] = {{0.f}};
  float4 xa[4], yb[4], xa2[4], yb2[4];

#define LOADF(XV, YV, D4)                                                        \
  {                                                                              \
    _Pragma("unroll") for (int a = 0; a < 4; ++a)                                \
        XV[a] = *reinterpret_cast<const float4*>(&xs[(ty + a * 16) * PITCH + (D4) * 4]); \
    _Pragma("unroll") for (int b = 0; b < 4; ++b)                                \
        YV[b] = *reinterpret_cast<const float4*>(&ys[(tx + b * 16) * PITCH + (D4) * 4]); \
  }

#define COMPUTEF(XV, YV)                                        \
  {                                                             \
    _Pragma("unroll") for (int a = 0; a < 4; ++a)               \
        _Pragma("unroll") for (int b = 0; b < 4; ++b) {         \
      acc4[a][b] += fabsf(XV[a].x - YV[b].x);                   \
      acc4[a][b] += fabsf(XV[a].y - YV[b].y);                   \
      acc4[a][b] += fabsf(XV[a].z - YV[b].z);                   \
      acc4[a][b] += fabsf(XV[a].w - YV[b].w);                   \
    }                                                           \
  }

  // 2-deep register software pipeline (R2-proven ping-pong pattern)
  LOADF(xa, yb, 0)
  for (int d4 = 0; d4 < DD / 4; d4 += 2) {
    LOADF(xa2, yb2, d4 + 1)
    COMPUTEF(xa, yb)
    if (d4 + 2 < DD / 4) LOADF(xa, yb, d4 + 2)
    COMPUTEF(xa2, yb2)
  }
#undef LOADF
#undef COMPUTEF

  // store S tile
#pragma unroll
  for (int a = 0; a < 4; ++a) {
    int i = i0 + ty + a * 16;
#pragma unroll
    for (int b = 0; b < 4; ++b) {
      int j = j0 + tx + b * 16;
      S[(size_t)i * MM + j] = -acc4[a][b];
    }
  }

  // row partials: row i = i0 + ty + a*16, reduce over tx lanes + b
#pragma unroll
  for (int a = 0; a < 4; ++a) {
    float m = -acc4[a][0];
#pragma unroll
    for (int b = 1; b < 4; ++b) m = fmaxf(m, -acc4[a][b]);
    float s = 0.f;
#pragma unroll
    for (int b = 0; b < 4; ++b) s += __expf(-acc4[a][b] - m);
#pragma unroll
    for (int off = 1; off < 16; off <<= 1) {
      float m2 = __shfl_xor(m, off, 64);
      float s2 = __shfl_xor(s, off, 64);
      merge_ms(m, s, m2, s2);
    }
    if (tx == 0) {
      int i = i0 + ty + a * 16;
      rowPM[(size_t)jt * NN + i] = m;
      rowPS[(size_t)jt * NN + i] = s;
    }
  }

  // col partials: col c = tx + b*16, reduce over a regs + ty via LDS
  __shared__ float lm[16][64];
  __shared__ float lsv[16][64];
#pragma unroll
  for (int b = 0; b < 4; ++b) {
    int c = tx + b * 16;
    float m = -acc4[0][b];
#pragma unroll
    for (int a = 1; a < 4; ++a) m = fmaxf(m, -acc4[a][b]);
    float s = 0.f;
#pragma unroll
    for (int a = 0; a < 4; ++a) s += __expf(-acc4[a][b] - m);
    lm[ty][c] = m;
    lsv[ty][c] = s;
  }
  __syncthreads();
  if (t < 64) {
    float m = lm[0][t], s = lsv[0][t];
#pragma unroll
    for (int k = 1; k < 16; ++k) merge_ms(m, s, lm[k][t], lsv[k][t]);
    colPM[(size_t)it * MM + j0 + t] = m;
    colPS[(size_t)it * MM + j0 + t] = s;
  }
}

// ---------------- K2: merge stats + weighted accumulation + final ----------
__global__ __launch_bounds__(256) void k_wacc(const float* __restrict__ S,
                                              const float* __restrict__ rowPM,
                                              const float* __restrict__ rowPS,
                                              const float* __restrict__ colPM,
                                              const float* __restrict__ colPS,
                                              float* __restrict__ bNum,
                                              float* __restrict__ bDen,
                                              int* __restrict__ counter,
                                              float* __restrict__ out) {
  const int bid = blockIdx.x;  // 64 blocks, rows [bid*16, bid*16+16)
  const int t = threadIdx.x;

  // --- col stats for cols 4t..4t+3: merge 16 stripe partials, in registers ---
  float4 cm = reinterpret_cast<const float4*>(colPM)[t];
  float4 cs = reinterpret_cast<const float4*>(colPS)[t];
#pragma unroll
  for (int k = 1; k < NTB; ++k) {
    float4 m2 = reinterpret_cast<const float4*>(colPM + (size_t)k * MM)[t];
    float4 s2 = reinterpret_cast<const float4*>(colPS + (size_t)k * MM)[t];
    merge_ms(cm.x, cs.x, m2.x, s2.x);
    merge_ms(cm.y, cs.y, m2.y, s2.y);
    merge_ms(cm.z, cs.z, m2.z, s2.z);
    merge_ms(cm.w, cs.w, m2.w, s2.w);
  }
  float4 ci;
  ci.x = 1.f / cs.x; ci.y = 1.f / cs.y; ci.z = 1.f / cs.z; ci.w = 1.f / cs.w;

  // --- row stats for this block's 16 rows ---
  __shared__ float rowMl[16], rowIl[16];
  if (t < 16) {
    int r = bid * 16 + t;
    float m = rowPM[r], s = rowPS[r];
#pragma unroll
    for (int k = 1; k < NTB; ++k)
      merge_ms(m, s, rowPM[(size_t)k * NN + r], rowPS[(size_t)k * NN + r]);
    rowMl[t] = m;
    rowIl[t] = 1.f / s;
  }
  __syncthreads();

  // --- weighted accumulation over 16 rows x 1024 cols ---
  float num = 0.f, den = 0.f;
  for (int rl = 0; rl < 16; ++rl) {
    int row = bid * 16 + rl;
    float4 v = reinterpret_cast<const float4*>(S + (size_t)row * MM)[t];
    float rm = rowMl[rl], ri = rowIl[rl];
#define DO_COMP(VX, CMX, CIX)               \
    {                                       \
      float a = __expf((VX) - rm) * ri;     \
      float b = __expf((VX) - (CMX)) * (CIX); \
      float w = a + b - a * b;              \
      num += w * (VX);                      \
      den += w;                             \
    }
    DO_COMP(v.x, cm.x, ci.x)
    DO_COMP(v.y, cm.y, ci.y)
    DO_COMP(v.z, cm.z, ci.z)
    DO_COMP(v.w, cm.w, ci.w)
#undef DO_COMP
  }

  // --- block reduce ---
  num = wredSum(num);
  den = wredSum(den);
  __shared__ float rn[4], rd[4];
  const int lane = t & 63, wv = t >> 6;
  if (lane == 0) { rn[wv] = num; rd[wv] = den; }
  __syncthreads();
  if (t == 0) {
    bNum[bid] = rn[0] + rn[1] + rn[2] + rn[3];
    bDen[bid] = rd[0] + rd[1] + rd[2] + rd[3];
  }

  // --- last-block-done final reduction (deterministic index-ordered sum) ---
  __shared__ int isLast;
  if (t == 0) {
    __threadfence();                       // publish bNum/bDen
    int ticket = atomicAdd(counter, 1);    // device-scope
    isLast = (ticket == 63) ? 1 : 0;
  }
  __syncthreads();
  if (isLast && t < 64) {
    __threadfence();                       // acquire others' bNum/bDen
    float n = bNum[t], d = bDen[t];
    n = wredSum(n);
    d = wredSum(d);
    if (t == 0) out[0] = n / d;
  }
}

// ---------------- launch ----------------
extern "C" void kernel_launch(void* const* d_in, const int* in_sizes, int n_in,
                              void* d_out, int out_size, void* d_ws, size_t ws_size,
                              hipStream_t stream) {
  const float* zx = (const float*)d_in[0];
  const float* zy = (const float*)d_in[1];
  float* out = (float*)d_out;

  float* ws = (float*)d_ws;
  float* S     = ws;                        // 1M floats
  float* rowPM = S + (size_t)NN * MM;       // 16K
  float* rowPS = rowPM + NTB * NN;          // 16K
  float* colPM = rowPS + NTB * NN;          // 16K
  float* colPS = colPM + NTB * MM;          // 16K
  float* bNum  = colPS + NTB * MM;          // 64
  float* bDen  = bNum + 64;                 // 64
  int*   counter = (int*)(bDen + 64);       // 1

  k_tile<<<dim3(NTB, NTB), 256, 0, stream>>>(zx, zy, S, rowPM, rowPS, colPM, colPS, counter);
  k_wacc<<<64, 256, 0, stream>>>(S, rowPM, rowPS, colPM, colPS, bNum, bDen, counter, out);
}

// Round 6
// 44.612 us; speedup vs baseline: 1.0106x; 1.0106x over previous
//
#include <hip/hip_runtime.h>
#include <math.h>

#define NN 1024
#define MM 1024
#define DD 256
#define TILE 64
#define NTB 16
#define PITCH 260  // 256 + 4 pad: conflict-free b128 reads (proven R1/R4)

__device__ inline void merge_ms(float& m, float& s, float m2, float s2) {
  float mn = fmaxf(m, m2);
  s = s * __expf(m - mn) + s2 * __expf(m2 - mn);
  m = mn;
}

__device__ inline float wredSum(float v) {
#pragma unroll
  for (int o = 32; o > 0; o >>= 1) v += __shfl_down(v, o, 64);
  return v;
}

// ---------------- K1: distance tile + S store + row/col softmax partials ----
// EXACT R4 k_tile (proven, no pipeline) + counter reset.
__global__ __launch_bounds__(256) void k_tile(const float* __restrict__ zx,
                                              const float* __restrict__ zy,
                                              float* __restrict__ S,
                                              float* __restrict__ rowPM,
                                              float* __restrict__ rowPS,
                                              float* __restrict__ colPM,
                                              float* __restrict__ colPS,
                                              int* __restrict__ counter) {
  __shared__ float xs[TILE * PITCH];
  __shared__ float ys[TILE * PITCH];
  const int it = blockIdx.y, jt = blockIdx.x;
  const int i0 = it * TILE, j0 = jt * TILE;
  const int t = threadIdx.x;
  const int tx = t & 15, ty = t >> 4;

  if (it == 0 && jt == 0 && t == 0) counter[0] = 0;  // graph-replay-safe reset

#pragma unroll
  for (int k = 0; k < 16; ++k) {
    int idx4 = t + k * 256;
    int r = idx4 >> 6;
    int c4 = idx4 & 63;
    float4 vx = reinterpret_cast<const float4*>(zx + (size_t)(i0 + r) * DD)[c4];
    float4 vy = reinterpret_cast<const float4*>(zy + (size_t)(j0 + r) * DD)[c4];
    *reinterpret_cast<float4*>(&xs[r * PITCH + c4 * 4]) = vx;
    *reinterpret_cast<float4*>(&ys[r * PITCH + c4 * 4]) = vy;
  }
  __syncthreads();

  float acc4[4][4] = {{0.f}};
  for (int d4 = 0; d4 < DD / 4; ++d4) {
    float4 xa[4], yb[4];
#pragma unroll
    for (int a = 0; a < 4; ++a)
      xa[a] = *reinterpret_cast<const float4*>(&xs[(ty + a * 16) * PITCH + d4 * 4]);
#pragma unroll
    for (int b = 0; b < 4; ++b)
      yb[b] = *reinterpret_cast<const float4*>(&ys[(tx + b * 16) * PITCH + d4 * 4]);
#pragma unroll
    for (int a = 0; a < 4; ++a)
#pragma unroll
      for (int b = 0; b < 4; ++b) {
        acc4[a][b] += fabsf(xa[a].x - yb[b].x) + fabsf(xa[a].y - yb[b].y) +
                      fabsf(xa[a].z - yb[b].z) + fabsf(xa[a].w - yb[b].w);
      }
  }

#pragma unroll
  for (int a = 0; a < 4; ++a) {
    int i = i0 + ty + a * 16;
#pragma unroll
    for (int b = 0; b < 4; ++b) {
      int j = j0 + tx + b * 16;
      S[(size_t)i * MM + j] = -acc4[a][b];
    }
  }

  // row partials
#pragma unroll
  for (int a = 0; a < 4; ++a) {
    float m = -acc4[a][0];
#pragma unroll
    for (int b = 1; b < 4; ++b) m = fmaxf(m, -acc4[a][b]);
    float s = 0.f;
#pragma unroll
    for (int b = 0; b < 4; ++b) s += __expf(-acc4[a][b] - m);
#pragma unroll
    for (int off = 1; off < 16; off <<= 1) {
      float m2 = __shfl_xor(m, off, 64);
      float s2 = __shfl_xor(s, off, 64);
      merge_ms(m, s, m2, s2);
    }
    if (tx == 0) {
      int i = i0 + ty + a * 16;
      rowPM[(size_t)jt * NN + i] = m;
      rowPS[(size_t)jt * NN + i] = s;
    }
  }

  // col partials
  __shared__ float lm[16][64];
  __shared__ float lsv[16][64];
#pragma unroll
  for (int b = 0; b < 4; ++b) {
    int c = tx + b * 16;
    float m = -acc4[0][b];
#pragma unroll
    for (int a = 1; a < 4; ++a) m = fmaxf(m, -acc4[a][b]);
    float s = 0.f;
#pragma unroll
    for (int a = 0; a < 4; ++a) s += __expf(-acc4[a][b] - m);
    lm[ty][c] = m;
    lsv[ty][c] = s;
  }
  __syncthreads();
  if (t < 64) {
    float m = lm[0][t], s = lsv[0][t];
#pragma unroll
    for (int k = 1; k < 16; ++k) merge_ms(m, s, lm[k][t], lsv[k][t]);
    colPM[(size_t)it * MM + j0 + t] = m;
    colPS[(size_t)it * MM + j0 + t] = s;
  }
}

// ---------------- K2: merge stats + weighted accumulation + final ----------
// 256 blocks x 4 rows: full CU coverage (fix for R5's 64-block version).
__global__ __launch_bounds__(256) void k_wacc(const float* __restrict__ S,
                                              const float* __restrict__ rowPM,
                                              const float* __restrict__ rowPS,
                                              const float* __restrict__ colPM,
                                              const float* __restrict__ colPS,
                                              float* __restrict__ bNum,
                                              float* __restrict__ bDen,
                                              int* __restrict__ counter,
                                              float* __restrict__ out) {
  const int bid = blockIdx.x;  // rows [bid*4, bid*4+4)
  const int t = threadIdx.x;

  // col stats for cols 4t..4t+3 (registers; duplicated per block but parallel)
  float4 cm = reinterpret_cast<const float4*>(colPM)[t];
  float4 cs = reinterpret_cast<const float4*>(colPS)[t];
#pragma unroll
  for (int k = 1; k < NTB; ++k) {
    float4 m2 = reinterpret_cast<const float4*>(colPM + (size_t)k * MM)[t];
    float4 s2 = reinterpret_cast<const float4*>(colPS + (size_t)k * MM)[t];
    merge_ms(cm.x, cs.x, m2.x, s2.x);
    merge_ms(cm.y, cs.y, m2.y, s2.y);
    merge_ms(cm.z, cs.z, m2.z, s2.z);
    merge_ms(cm.w, cs.w, m2.w, s2.w);
  }
  float4 ci;
  ci.x = 1.f / cs.x; ci.y = 1.f / cs.y; ci.z = 1.f / cs.z; ci.w = 1.f / cs.w;

  // row stats for this block's 4 rows
  __shared__ float rowMl[4], rowIl[4];
  if (t < 4) {
    int r = bid * 4 + t;
    float m = rowPM[r], s = rowPS[r];
#pragma unroll
    for (int k = 1; k < NTB; ++k)
      merge_ms(m, s, rowPM[(size_t)k * NN + r], rowPS[(size_t)k * NN + r]);
    rowMl[t] = m;
    rowIl[t] = 1.f / s;
  }
  __syncthreads();

  // weighted accumulation over 4 rows x 1024 cols
  float num = 0.f, den = 0.f;
#pragma unroll
  for (int rl = 0; rl < 4; ++rl) {
    int row = bid * 4 + rl;
    float4 v = reinterpret_cast<const float4*>(S + (size_t)row * MM)[t];
    float rm = rowMl[rl], ri = rowIl[rl];
#define DO_COMP(VX, CMX, CIX)                 \
    {                                         \
      float a = __expf((VX) - rm) * ri;       \
      float b = __expf((VX) - (CMX)) * (CIX); \
      float w = a + b - a * b;                \
      num += w * (VX);                        \
      den += w;                               \
    }
    DO_COMP(v.x, cm.x, ci.x)
    DO_COMP(v.y, cm.y, ci.y)
    DO_COMP(v.z, cm.z, ci.z)
    DO_COMP(v.w, cm.w, ci.w)
#undef DO_COMP
  }

  // block reduce
  num = wredSum(num);
  den = wredSum(den);
  __shared__ float rn[4], rd[4];
  const int lane = t & 63, wv = t >> 6;
  if (lane == 0) { rn[wv] = num; rd[wv] = den; }
  __syncthreads();
  if (t == 0) {
    bNum[bid] = rn[0] + rn[1] + rn[2] + rn[3];
    bDen[bid] = rd[0] + rd[1] + rd[2] + rd[3];
  }

  // last-block-done final reduction (deterministic index-ordered sum)
  __shared__ int isLast;
  if (t == 0) {
    __threadfence();
    int ticket = atomicAdd(counter, 1);
    isLast = (ticket == 255) ? 1 : 0;
  }
  __syncthreads();
  if (isLast) {
    __threadfence();
    float n = bNum[t];
    float d = bDen[t];
    n = wredSum(n);
    d = wredSum(d);
    if (lane == 0) { rn[wv] = n; rd[wv] = d; }
    __syncthreads();
    if (t == 0) out[0] = (rn[0] + rn[1] + rn[2] + rn[3]) / (rd[0] + rd[1] + rd[2] + rd[3]);
  }
}

// ---------------- launch ----------------
extern "C" void kernel_launch(void* const* d_in, const int* in_sizes, int n_in,
                              void* d_out, int out_size, void* d_ws, size_t ws_size,
                              hipStream_t stream) {
  const float* zx = (const float*)d_in[0];
  const float* zy = (const float*)d_in[1];
  float* out = (float*)d_out;

  float* ws = (float*)d_ws;
  float* S     = ws;                        // 1M floats
  float* rowPM = S + (size_t)NN * MM;       // 16K
  float* rowPS = rowPM + NTB * NN;          // 16K
  float* colPM = rowPS + NTB * NN;          // 16K
  float* colPS = colPM + NTB * MM;          // 16K
  float* bNum  = colPS + NTB * MM;          // 256
  float* bDen  = bNum + 256;                // 256
  int*   counter = (int*)(bDen + 256);      // 1

  k_tile<<<dim3(NTB, NTB), 256, 0, stream>>>(zx, zy, S, rowPM, rowPS, colPM, colPS, counter);
  k_wacc<<<256, 256, 0, stream>>>(S, rowPM, rowPS, colPM, colPS, bNum, bDen, counter, out);
}